// Round 1
// baseline (25.714 us; speedup 1.0000x reference)
//
#include <hip/hip_runtime.h>

// out[b,s,d] = C[idx[b,s], d] + scale(s) * P[s, d]
// B=8, S=2048, V=50257, D=1024, fp32.
// scale(s) = (s - (S-1)/2) / std(arange(S)),  std = sqrt((S^2-1)/12)

constexpr int SEQ = 2048;
constexpr int DIM = 1024;
constexpr int ROWS = 8 * SEQ;            // 16384 output rows
// population std of arange(2048) = sqrt((2048^2 - 1)/12)
#define POS_STD 591.2066058f
#define POS_MEAN 1023.5f

__global__ __launch_bounds__(256) void embed_add_pos_kernel(
    const int* __restrict__ idx,      // [B*S]
    const float* __restrict__ C,      // [V, D]
    const float* __restrict__ P,      // [S, D]
    float* __restrict__ out)          // [B*S, D]
{
    const int row = blockIdx.x;              // one block per (b,s) row
    const int s = row & (SEQ - 1);
    const int tok = idx[row];                // uniform across block -> scalar load

    const float scale = ((float)s - POS_MEAN) / POS_STD;

    const float4* __restrict__ c4 = (const float4*)(C + (size_t)tok * DIM);
    const float4* __restrict__ p4 = (const float4*)(P + (size_t)s * DIM);
    float4* __restrict__ o4 = (float4*)(out + (size_t)row * DIM);

    const int d = threadIdx.x;               // 256 threads x float4 = 1024 floats
    const float4 c = c4[d];
    const float4 p = p4[d];
    float4 r;
    r.x = fmaf(scale, p.x, c.x);
    r.y = fmaf(scale, p.y, c.y);
    r.z = fmaf(scale, p.z, c.z);
    r.w = fmaf(scale, p.w, c.w);
    o4[d] = r;
}

extern "C" void kernel_launch(void* const* d_in, const int* in_sizes, int n_in,
                              void* d_out, int out_size, void* d_ws, size_t ws_size,
                              hipStream_t stream) {
    const int*   idx = (const int*)d_in[0];     // inputs [B,S] (int32)
    const float* C   = (const float*)d_in[1];   // content_kernel [V,D]
    const float* P   = (const float*)d_in[2];   // position_kernel [S,D]
    float* out = (float*)d_out;

    embed_add_pos_kernel<<<ROWS, 256, 0, stream>>>(idx, C, P, out);
}

// Round 3
// 25.215 us; speedup vs baseline: 1.0198x; 1.0198x over previous
//
#include <hip/hip_runtime.h>

// out[b,s,d] = C[idx[b,s], d] + scale(s) * P[s, d]
// B=8, S=2048, V=50257, D=1024, fp32.
// scale(s) = (s - (S-1)/2) / std(arange(S)),  std = sqrt((S^2-1)/12)

constexpr int SEQ = 2048;
constexpr int DIM = 1024;
constexpr int ROWS = 8 * SEQ;            // 16384 output rows
// population std of arange(2048) = sqrt((2048^2 - 1)/12)
#define POS_STD 591.2066058f
#define POS_MEAN 1023.5f

typedef float f32x4 __attribute__((ext_vector_type(4)));  // native vector: OK for nontemporal builtins

__global__ __launch_bounds__(256) void embed_add_pos_kernel(
    const int* __restrict__ idx,      // [B*S]
    const float* __restrict__ C,      // [V, D]
    const float* __restrict__ P,      // [S, D]
    float* __restrict__ out)          // [B*S, D]
{
    const int row = blockIdx.x;              // one block per (b,s) row
    const int s = row & (SEQ - 1);
    const int tok = idx[row];                // uniform across block -> scalar load

    const float scale = ((float)s - POS_MEAN) / POS_STD;

    const f32x4* __restrict__ c4 = (const f32x4*)(C + (size_t)tok * DIM);
    const f32x4* __restrict__ p4 = (const f32x4*)(P + (size_t)s * DIM);
    f32x4* __restrict__ o4 = (f32x4*)(out + (size_t)row * DIM);

    const int d = threadIdx.x;               // 256 threads x float4 = 1024 floats
    const f32x4 c = c4[d];
    const f32x4 p = p4[d];
    f32x4 r;
    r.x = fmaf(scale, p.x, c.x);
    r.y = fmaf(scale, p.y, c.y);
    r.z = fmaf(scale, p.z, c.z);
    r.w = fmaf(scale, p.w, c.w);
    // Output is write-once, never re-read: stream it past L2 so the cache
    // keeps the gathered content rows (dup tokens) + position rows (8x reuse).
    __builtin_nontemporal_store(r, &o4[d]);
}

extern "C" void kernel_launch(void* const* d_in, const int* in_sizes, int n_in,
                              void* d_out, int out_size, void* d_ws, size_t ws_size,
                              hipStream_t stream) {
    const int*   idx = (const int*)d_in[0];     // inputs [B,S] (int32)
    const float* C   = (const float*)d_in[1];   // content_kernel [V,D]
    const float* P   = (const float*)d_in[2];   // position_kernel [S,D]
    float* out = (float*)d_out;

    embed_add_pos_kernel<<<ROWS, 256, 0, stream>>>(idx, C, P, out);
}